// Round 2
// baseline (159.453 us; speedup 1.0000x reference)
//
#include <hip/hip_runtime.h>
#include <hip/hip_bf16.h>

// Problem constants (B=1)
#define S_LEN 2048
#define E_DIM 1024
#define NH    16
#define HD    64
#define SM_SCALE 0.5f

typedef short bf16x8_t  __attribute__((ext_vector_type(8)));    // 8 bf16 = 4 VGPRs
typedef float f32x4_t   __attribute__((ext_vector_type(4)));
typedef float f32x16_t  __attribute__((ext_vector_type(16)));
typedef __bf16 bf16x4_t __attribute__((ext_vector_type(4)));

static __device__ __forceinline__ unsigned short f2bf_bits(float f) {
    return __builtin_bit_cast(unsigned short, (__bf16)f);
}

// v_cvt_pk_bf16_f32: dst.lo = bf16(lo), dst.hi = bf16(hi)  (RNE, same as (__bf16) cast)
static __device__ __forceinline__ unsigned int cvt_pk_bf16(float lo, float hi) {
    unsigned int r;
    asm("v_cvt_pk_bf16_f32 %0, %1, %2" : "=v"(r) : "v"(lo), "v"(hi));
    return r;
}

// async global->LDS, 16B per lane, dest = wave-uniform base + lane*16
#define GLD16(gp, lp) __builtin_amdgcn_global_load_lds(                       \
    (const __attribute__((address_space(1))) void*)(gp),                      \
    (__attribute__((address_space(3))) void*)(lp), 16, 0, 0)

// counted vmem wait (T4): leave N newest vmem ops in flight
#define WAITVM(N) asm volatile("s_waitcnt vmcnt(" #N ")" ::: "memory")

// -------------------------------------------- merged prep: W^T + x->bf16
__global__ void k_prep(const float* __restrict__ x,
                       const float* __restrict__ Wq, const float* __restrict__ Wk,
                       const float* __restrict__ Wv, const float* __restrict__ Wo,
                       __bf16* __restrict__ xb, __bf16* __restrict__ wt) {
    const int z = blockIdx.z;
    if (z < 4) {
        __shared__ float tile[32][33];
        const float* W = z == 0 ? Wq : z == 1 ? Wk : z == 2 ? Wv : Wo;
        __bf16* o = wt + (size_t)z * E_DIM * E_DIM;
        const int tx = threadIdx.x, ty = threadIdx.y;
        const int bx = blockIdx.x * 32, by = blockIdx.y * 32;
#pragma unroll
        for (int j = 0; j < 32; j += 8)
            tile[ty + j][tx] = W[(size_t)(by + ty + j) * E_DIM + bx + tx];
        __syncthreads();
#pragma unroll
        for (int j = 0; j < 32; j += 8)
            o[(size_t)(bx + ty + j) * E_DIM + by + tx] = (__bf16)tile[tx][ty + j];
    } else {
        const int bid = (z - 4) * 1024 + blockIdx.y * 32 + blockIdx.x;
        const int tid = threadIdx.y * 32 + threadIdx.x;
        const int i = bid * 256 + tid;
        const float4 v = ((const float4*)x)[i];
        bf16x4_t o4;
        o4.x = (__bf16)v.x; o4.y = (__bf16)v.y; o4.z = (__bf16)v.z; o4.w = (__bf16)v.w;
        ((bf16x4_t*)xb)[i] = o4;
    }
}

// ------------------------------------------------------- QKV projection GEMM
// 128x128 tile, BK=32. 3-buffer ring + counted vmcnt + raw s_barrier (T4):
// tile t lives in buf t%3; per iter: wait(tile k) -> barrier -> issue tile k+2
// -> compute tile k. Tile k's loads get ~2 iterations of latency cover; the
// prefetch is never drained by a vmcnt(0) barrier.
// Epilogue scatters into 32x32x16-MFMA operand-native layout (unchanged):
//   Q (B-op): [h][qt][rb2][kc4][lane64][j8]  rb=(s&63)>>5, lane=(s&31)+((d>>3)&1)*32, kc=d>>4, j=d&7
//   K (A-op): same index function as Q
//   V (A-op, V^T): [h][kt][db2][kc4][lane64][j8] db=d>>5, lane=(d&31)+((key>>3)&1)*32, kc=(key&63)>>4, j=key&7
__global__ __launch_bounds__(256) void k_gemm_qkv(
    const __bf16* __restrict__ xb, const __bf16* __restrict__ wt,
    const float* __restrict__ bq, const float* __restrict__ bk, const float* __restrict__ bv,
    __bf16* __restrict__ qkv) {
    __shared__ __align__(16) unsigned short As[3][4096];   // 3 x 8KB
    __shared__ __align__(16) unsigned short Bs[3][4096];   // 3 x 8KB

    const int z = blockIdx.z;
    const __bf16* Bt = wt + (size_t)z * E_DIM * E_DIM;      // W^T [n][k]
    const float* bias = z == 0 ? bq : z == 1 ? bk : bv;
    __bf16* out = qkv + (size_t)z * NH * S_LEN * HD;

    const int tid = threadIdx.x, w = tid >> 6, l = tid & 63;
    const int lm = l & 15, q4 = l >> 4;
    const int bm = blockIdx.y, bn = blockIdx.x;
    const int wm = w >> 1, wn = w & 1;

    const int sm = (w << 4) + (l >> 2);
    const int skk = (l & 3) << 3;
    const __bf16* Ag = xb + (size_t)(bm * 128 + sm) * E_DIM + skk;
    const __bf16* Bg = Bt + (size_t)(bn * 128 + sm) * E_DIM + skk;
    const int woff = w << 9;

    auto stage = [&](int t) {
        const int buf = t % 3;
        const int kk = t * 32;
        GLD16(Ag + kk,                        &As[buf][woff]);
        GLD16(Ag + (size_t)64 * E_DIM + kk,   &As[buf][woff + 2048]);
        GLD16(Bg + kk,                        &Bs[buf][woff]);
        GLD16(Bg + (size_t)64 * E_DIM + kk,   &Bs[buf][woff + 2048]);
    };

    f32x4_t acc[4][4];
#pragma unroll
    for (int i = 0; i < 4; i++)
#pragma unroll
        for (int j = 0; j < 4; j++) { acc[i][j].x = 0.f; acc[i][j].y = 0.f; acc[i][j].z = 0.f; acc[i][j].w = 0.f; }

    stage(0);
    stage(1);

    for (int k = 0; k < 32; k++) {
        const int bb = k % 3;
        if (k < 31) WAITVM(4);    // tile k done; tile k+1 (4 loads) stays in flight
        else        WAITVM(0);
        __builtin_amdgcn_s_barrier();
        if (k + 2 < 32) stage(k + 2);

        bf16x8_t af[4], bfr[4];
#pragma unroll
        for (int mt = 0; mt < 4; mt++)
            af[mt] = *(const bf16x8_t*)&As[bb][(wm * 64 + mt * 16 + lm) * 32 + q4 * 8];
#pragma unroll
        for (int nt = 0; nt < 4; nt++)
            bfr[nt] = *(const bf16x8_t*)&Bs[bb][(wn * 64 + nt * 16 + lm) * 32 + q4 * 8];
#pragma unroll
        for (int mt = 0; mt < 4; mt++)
#pragma unroll
            for (int nt = 0; nt < 4; nt++)
                acc[mt][nt] = __builtin_amdgcn_mfma_f32_16x16x32_bf16(af[mt], bfr[nt], acc[mt][nt], 0, 0, 0);
    }

    // C row s = bm*128 + wm*64 + mt*16 + q4*4 + i ; col n = bn*128 + wn*64 + nt*16 + lm
#pragma unroll
    for (int nt = 0; nt < 4; nt++) {
        const int n = bn * 128 + wn * 64 + nt * 16 + lm;
        const float bval = bias[n];
        const int h = n >> 6, d = n & 63;
        const int tile0 = bm * 2 + wm;          // s>>6
        if (z == 2) {
            // V A-op-native: key = mt*16 + q4*4 + i (local in tile)
            const int db = d >> 5, dl = d & 31;
#pragma unroll
            for (int mt = 0; mt < 4; mt++) {
                __bf16* ob = out + (((size_t)h * 32 + tile0) * 8 + db * 4 + mt) * 512
                                 + (dl + (q4 >> 1) * 32) * 8 + (q4 & 1) * 4;
                union { unsigned short s4[4]; uint2 u; } pk;
#pragma unroll
                for (int i = 0; i < 4; i++) pk.s4[i] = f2bf_bits(acc[mt][nt][i] + bval);
                *(uint2*)ob = pk.u;
            }
        } else {
            // Q/K op-native: s_local = mt*16 + q4*4 + i, rb = mt>>1
            const float scale = (z == 0) ? SM_SCALE : 1.0f;   // fold SM_SCALE into Q (exact: pow2)
            const int kc = d >> 4, khalf = (d >> 3) & 1, j = d & 7;
#pragma unroll
            for (int mt = 0; mt < 4; mt++) {
                __bf16* ob = out + (((size_t)h * 32 + tile0) * 8 + (mt >> 1) * 4 + kc) * 512
                                 + ((mt & 1) * 16 + q4 * 4 + khalf * 32) * 8 + j;
#pragma unroll
                for (int i = 0; i < 4; i++)
                    ob[i * 8] = (__bf16)((acc[mt][nt][i] + bval) * scale);
            }
        }
    }
}

// ------------------------------------------------------------- attention
// 32x32x16 MFMA. 4 waves = (row-half rh = w&1) x (key-half kh = w>>1).
// Wave (rh,kh): S^T(32k x 32r) = K_kh · Q_rh^T in 4 MFMA, O^T(64d x 32r) +=
// V^T·P in 4 MFMA. P fully in-register (T12 cvt_pk + permlane32_swap).
// K/V tiles in a 3-buffer ring with counted vmcnt + raw s_barrier (T4):
// per iter: wait(tile s; leave tile s+1 in flight) -> barrier -> issue tile
// s+2 -> compute tile s. No per-iteration vmcnt(0) drain.
// Key-half partials combine linearly at end (no-max softmax, scores bounded).
__global__ __launch_bounds__(256, 2) void k_attn(
    const __bf16* __restrict__ Qf, const __bf16* __restrict__ Kf, const __bf16* __restrict__ Vf,
    __bf16* __restrict__ attn) {
    __shared__ __align__(16) unsigned short KVs[3][2][4096];  // [ring buf][K/V][8KB tile]

    // work-balanced swizzle: long q-tiles dispatched first
    const int b = blockIdx.x;
    int qt, h;
    if (b < 256) { qt = 16 + (b >> 4); h = b & 15; }
    else         { qt = 15 - ((b - 256) >> 4); h = (b - 256) & 15; }

    const int tid = threadIdx.x, w = tid >> 6, l = tid & 63;
    const int rh = w & 1, kh = w >> 1;
    const int l31 = l & 31, lh = l >> 5;

    const __bf16* Qb = Qf + ((size_t)h * 32 + qt) * 4096;
    const __bf16* Kb = Kf + (size_t)h * 32 * 4096;
    const __bf16* Vb = Vf + (size_t)h * 32 * 4096;

    auto stage = [&](int t) {
        const int buf = t % 3;
        const __bf16* Kg = Kb + (size_t)t * 4096;
        const __bf16* Vg = Vb + (size_t)t * 4096;
        GLD16(Kg + (w << 9) + l * 8,       &KVs[buf][0][(w << 9) + l * 8]);
        GLD16(Kg + ((w + 4) << 9) + l * 8, &KVs[buf][0][((w + 4) << 9) + l * 8]);
        GLD16(Vg + (w << 9) + l * 8,       &KVs[buf][1][(w << 9) + l * 8]);
        GLD16(Vg + ((w + 4) << 9) + l * 8, &KVs[buf][1][((w + 4) << 9) + l * 8]);
    };

    // Q B-frags pinned (pre-scaled by SM_SCALE): rows rh*32..+31, 4 k-chunks
    bf16x8_t qf[4];
#pragma unroll
    for (int kc = 0; kc < 4; kc++)
        qf[kc] = *(const bf16x8_t*)(Qb + ((rh * 4 + kc) << 9) + l * 8);

    float lacc = 0.f;
    f32x16_t oacc[2];
#pragma unroll
    for (int db = 0; db < 2; db++)
#pragma unroll
        for (int r = 0; r < 16; r++) oacc[db][r] = 0.f;

    // drain qf loads so in-loop vmcnt counts are pure GLD16 counts
    WAITVM(0);
    stage(0);
    if (qt >= 1) stage(1);

    for (int s = 0; s <= qt; s++) {
        const int bb = s % 3;
        if (s < qt) WAITVM(4);    // tile s done; tile s+1 (4 loads) stays in flight
        else        WAITVM(0);
        __builtin_amdgcn_s_barrier();
        if (s + 2 <= qt) stage(s + 2);

        const bool diag = (s == qt);
        if (!(diag && kh > rh)) {          // (rh=0,kh=1) diag block fully masked
            // S^T = K·Q^T : D[key = (reg&3)+8*(reg>>2)+4*lh][row = l31]
            f32x16_t st;
#pragma unroll
            for (int r = 0; r < 16; r++) st[r] = 0.f;
            __builtin_amdgcn_s_setprio(1);
#pragma unroll
            for (int kc = 0; kc < 4; kc++) {
                bf16x8_t kf = *(const bf16x8_t*)&KVs[bb][0][((kh * 4 + kc) << 9) + l * 8];
                st = __builtin_amdgcn_mfma_f32_32x32x16_bf16(kf, qf[kc], st, 0, 0, 0);
            }
            __builtin_amdgcn_s_setprio(0);
            // exp (+ causal mask only on the diagonal kh==rh block)
            if (diag && kh == rh) {
#pragma unroll
                for (int r = 0; r < 16; r++) {
                    const int keyl = (r & 3) + 8 * (r >> 2) + 4 * lh;
                    st[r] = (keyl > l31) ? 0.f : __expf(st[r]);
                }
            } else {
#pragma unroll
                for (int r = 0; r < 16; r++) st[r] = __expf(st[r]);
            }
#pragma unroll
            for (int r = 0; r < 16; r++) lacc += st[r];
            // O^T += V^T·P : A = V frags, B = P frags built fully in-register.
            // c covers keys kh*32 + c*16 + {0..15}; st regs c*8.. c*8+7 hold them.
#pragma unroll
            for (int c = 0; c < 2; c++) {
                unsigned int v0 = cvt_pk_bf16(st[c * 8 + 0], st[c * 8 + 1]);
                unsigned int v1 = cvt_pk_bf16(st[c * 8 + 2], st[c * 8 + 3]);
                unsigned int v2 = cvt_pk_bf16(st[c * 8 + 4], st[c * 8 + 5]);
                unsigned int v3 = cvt_pk_bf16(st[c * 8 + 6], st[c * 8 + 7]);
                // a' = [a.lo | b.lo], b' = [a.hi | b.hi] across the lane<32/>=32 halves
                asm("v_permlane32_swap_b32 %0, %1" : "+v"(v0), "+v"(v2));
                asm("v_permlane32_swap_b32 %0, %1" : "+v"(v1), "+v"(v3));
                union { unsigned int u4[4]; bf16x8_t v; } pku;
                pku.u4[0] = v0; pku.u4[1] = v1; pku.u4[2] = v2; pku.u4[3] = v3;
                __builtin_amdgcn_s_setprio(1);
#pragma unroll
                for (int db = 0; db < 2; db++) {
                    bf16x8_t vf = *(const bf16x8_t*)&KVs[bb][1][((db * 4 + kh * 2 + c) << 9) + l * 8];
                    oacc[db] = __builtin_amdgcn_mfma_f32_32x32x16_bf16(vf, pku.v, oacc[db], 0, 0, 0);
                }
                __builtin_amdgcn_s_setprio(0);
            }
        }
    }

    // ---- key-half combine (linear: no-max softmax) ----
    __syncthreads();                        // all waves done with KVs; reuse as exchange
    float* Ex = (float*)KVs;                // [rh*64 + lane][34]: 32 O + lacc
    if (kh == 1) {
        float* e = Ex + (rh * 64 + l) * 34;
#pragma unroll
        for (int db = 0; db < 2; db++)
#pragma unroll
            for (int r = 0; r < 16; r++) e[db * 16 + r] = oacc[db][r];
        e[32] = lacc;
    }
    __syncthreads();
    if (kh == 0) {
        const float* e = Ex + (rh * 64 + l) * 34;
#pragma unroll
        for (int db = 0; db < 2; db++)
#pragma unroll
            for (int r = 0; r < 16; r++) oacc[db][r] += e[db * 16 + r];
        lacc += e[32];
        lacc += __shfl_xor(lacc, 32, 64);   // lanes l31 / l31+32 hold same row
        const float rl = 1.f / lacc;
        const int row = qt * 64 + rh * 32 + l31;
#pragma unroll
        for (int db = 0; db < 2; db++)
#pragma unroll
            for (int a = 0; a < 4; a++) {
                union { unsigned short s4[4]; uint2 u; } pk;
#pragma unroll
                for (int i = 0; i < 4; i++) pk.s4[i] = f2bf_bits(oacc[db][a * 4 + i] * rl);
                *(uint2*)(attn + (size_t)row * E_DIM + h * HD + db * 32 + a * 8 + lh * 4) = pk.u;
            }
    }
}

// --------------------------------------------------------- output projection
// 64x128 tile, 3-buffer ring + counted vmcnt + raw s_barrier (1 block/CU ->
// pipeline is the only latency cover available).
__global__ __launch_bounds__(256) void k_gemm_out(
    const __bf16* __restrict__ A, const __bf16* __restrict__ Bt,
    const float* __restrict__ bias, float* __restrict__ out) {
    __shared__ __align__(16) unsigned short As[3][2048];   // 3 x 4KB
    __shared__ __align__(16) unsigned short Bs[3][4096];   // 3 x 8KB

    const int tid = threadIdx.x, w = tid >> 6, l = tid & 63;
    const int lm = l & 15, q4 = l >> 4;
    const int bm = blockIdx.y, bn = blockIdx.x;
    const int wm = w >> 1, wn = w & 1;

    const int sm = (w << 4) + (l >> 2);
    const int skk = (l & 3) << 3;
    const __bf16* Ag = A + (size_t)(bm * 64 + sm) * E_DIM + skk;
    const __bf16* Bg = Bt + (size_t)(bn * 128 + sm) * E_DIM + skk;
    const int woff = w << 9;

    auto stage = [&](int t) {
        const int buf = t % 3;
        const int kk = t * 32;
        GLD16(Ag + kk,                      &As[buf][woff]);
        GLD16(Bg + kk,                      &Bs[buf][woff]);
        GLD16(Bg + (size_t)64 * E_DIM + kk, &Bs[buf][woff + 2048]);
    };

    f32x4_t acc[2][4];
#pragma unroll
    for (int i = 0; i < 2; i++)
#pragma unroll
        for (int j = 0; j < 4; j++) { acc[i][j].x = 0.f; acc[i][j].y = 0.f; acc[i][j].z = 0.f; acc[i][j].w = 0.f; }

    stage(0);
    stage(1);

    for (int s = 0; s < 32; s++) {
        const int bb = s % 3;
        if (s < 31) WAITVM(3);    // tile s done; tile s+1 (3 loads) stays in flight
        else        WAITVM(0);
        __builtin_amdgcn_s_barrier();
        if (s + 2 < 32) stage(s + 2);

        bf16x8_t af[2], bfr[4];
#pragma unroll
        for (int mt = 0; mt < 2; mt++)
            af[mt] = *(const bf16x8_t*)&As[bb][(wm * 32 + mt * 16 + lm) * 32 + q4 * 8];
#pragma unroll
        for (int nt = 0; nt < 4; nt++)
            bfr[nt] = *(const bf16x8_t*)&Bs[bb][(wn * 64 + nt * 16 + lm) * 32 + q4 * 8];
#pragma unroll
        for (int mt = 0; mt < 2; mt++)
#pragma unroll
            for (int nt = 0; nt < 4; nt++)
                acc[mt][nt] = __builtin_amdgcn_mfma_f32_16x16x32_bf16(af[mt], bfr[nt], acc[mt][nt], 0, 0, 0);
    }

#pragma unroll
    for (int nt = 0; nt < 4; nt++) {
        const int n = bn * 128 + wn * 64 + nt * 16 + lm;
        const float bval = bias[n];
#pragma unroll
        for (int mt = 0; mt < 2; mt++) {
            const int r0 = bm * 64 + wm * 32 + mt * 16 + q4 * 4;
#pragma unroll
            for (int i = 0; i < 4; i++)
                out[(size_t)(r0 + i) * E_DIM + n] = acc[mt][nt][i] + bval;
        }
    }
}

extern "C" void kernel_launch(void* const* d_in, const int* in_sizes, int n_in,
                              void* d_out, int out_size, void* d_ws, size_t ws_size,
                              hipStream_t stream) {
    const float* x  = (const float*)d_in[0];
    const float* Wq = (const float*)d_in[1];
    const float* bq = (const float*)d_in[2];
    const float* Wk = (const float*)d_in[3];
    const float* bk = (const float*)d_in[4];
    const float* Wv = (const float*)d_in[5];
    const float* bv = (const float*)d_in[6];
    const float* Wo = (const float*)d_in[7];
    const float* bo = (const float*)d_in[8];
    float* out = (float*)d_out;

    char* ws = (char*)d_ws;
    __bf16* xb   = (__bf16*)(ws);                        // 4 MB  x bf16 [S][E]
    __bf16* wt   = (__bf16*)(ws + ((size_t)4  << 20));   // 4x2MB [Wq^T,Wk^T,Wv^T,Wo^T] bf16
    __bf16* qkv  = (__bf16*)(ws + ((size_t)12 << 20));   // op-native Qf,Kf,Vf (4MB each)
    __bf16* attn = (__bf16*)(ws + ((size_t)24 << 20));   // 4 MB  [S][E] bf16

    k_prep<<<dim3(32, 32, 6), dim3(32, 8), 0, stream>>>(x, Wq, Wk, Wv, Wo, xb, wt);
    k_gemm_qkv<<<dim3(E_DIM / 128, S_LEN / 128, 3), 256, 0, stream>>>(xb, wt, bq, bk, bv, qkv);
    k_attn<<<dim3(512), 256, 0, stream>>>(
        qkv, qkv + (size_t)NH * S_LEN * HD, qkv + (size_t)2 * NH * S_LEN * HD, attn);
    k_gemm_out<<<dim3(E_DIM / 128, S_LEN / 64), 256, 0, stream>>>(
        attn, wt + (size_t)3 * E_DIM * E_DIM, bo, out);
}

// Round 3
// 151.973 us; speedup vs baseline: 1.0492x; 1.0492x over previous
//
#include <hip/hip_runtime.h>
#include <hip/hip_bf16.h>

// Problem constants (B=1)
#define S_LEN 2048
#define E_DIM 1024
#define NH    16
#define HD    64
#define SM_SCALE 0.5f

typedef short bf16x8_t  __attribute__((ext_vector_type(8)));    // 8 bf16 = 4 VGPRs
typedef float f32x4_t   __attribute__((ext_vector_type(4)));
typedef float f32x16_t  __attribute__((ext_vector_type(16)));
typedef __bf16 bf16x4_t __attribute__((ext_vector_type(4)));

static __device__ __forceinline__ unsigned short f2bf_bits(float f) {
    return __builtin_bit_cast(unsigned short, (__bf16)f);
}

// v_cvt_pk_bf16_f32: dst.lo = bf16(lo), dst.hi = bf16(hi)  (RNE, same as (__bf16) cast)
static __device__ __forceinline__ unsigned int cvt_pk_bf16(float lo, float hi) {
    unsigned int r;
    asm("v_cvt_pk_bf16_f32 %0, %1, %2" : "=v"(r) : "v"(lo), "v"(hi));
    return r;
}

// async global->LDS, 16B per lane, dest = wave-uniform base + lane*16
#define GLD16(gp, lp) __builtin_amdgcn_global_load_lds(                       \
    (const __attribute__((address_space(1))) void*)(gp),                      \
    (__attribute__((address_space(3))) void*)(lp), 16, 0, 0)

// -------------------------------------------- merged prep: W^T + x->bf16
__global__ void k_prep(const float* __restrict__ x,
                       const float* __restrict__ Wq, const float* __restrict__ Wk,
                       const float* __restrict__ Wv, const float* __restrict__ Wo,
                       __bf16* __restrict__ xb, __bf16* __restrict__ wt) {
    const int z = blockIdx.z;
    if (z < 4) {
        __shared__ float tile[32][33];
        const float* W = z == 0 ? Wq : z == 1 ? Wk : z == 2 ? Wv : Wo;
        __bf16* o = wt + (size_t)z * E_DIM * E_DIM;
        const int tx = threadIdx.x, ty = threadIdx.y;
        const int bx = blockIdx.x * 32, by = blockIdx.y * 32;
#pragma unroll
        for (int j = 0; j < 32; j += 8)
            tile[ty + j][tx] = W[(size_t)(by + ty + j) * E_DIM + bx + tx];
        __syncthreads();
#pragma unroll
        for (int j = 0; j < 32; j += 8)
            o[(size_t)(bx + ty + j) * E_DIM + by + tx] = (__bf16)tile[tx][ty + j];
    } else {
        const int bid = (z - 4) * 1024 + blockIdx.y * 32 + blockIdx.x;
        const int tid = threadIdx.y * 32 + threadIdx.x;
        const int i = bid * 256 + tid;
        const float4 v = ((const float4*)x)[i];
        bf16x4_t o4;
        o4.x = (__bf16)v.x; o4.y = (__bf16)v.y; o4.z = (__bf16)v.z; o4.w = (__bf16)v.w;
        ((bf16x4_t*)xb)[i] = o4;
    }
}

// ------------------------------------------------------- QKV projection GEMM
// 128x128 tile, BK=32 (m97 structure, R1 form — R2's manual vmcnt ring
// regressed: order-pinning defeats compiler scheduling, m141 lesson).
// Epilogue scatters into 32x32x16-MFMA operand-native layout:
//   Q (B-op): [h][qt][rb2][kc4][lane64][j8]  rb=(s&63)>>5, lane=(s&31)+((d>>3)&1)*32, kc=d>>4, j=d&7
//   K (A-op): same index function as Q
//   V (A-op, V^T): [h][kt][db2][kc4][lane64][j8] db=d>>5, lane=(d&31)+((key>>3)&1)*32, kc=(key&63)>>4, j=key&7
__global__ __launch_bounds__(256) void k_gemm_qkv(
    const __bf16* __restrict__ xb, const __bf16* __restrict__ wt,
    const float* __restrict__ bq, const float* __restrict__ bk, const float* __restrict__ bv,
    __bf16* __restrict__ qkv) {
    __shared__ __align__(16) unsigned short As[128 * 32];
    __shared__ __align__(16) unsigned short Bs[128 * 32];

    const int z = blockIdx.z;
    const __bf16* Bt = wt + (size_t)z * E_DIM * E_DIM;      // W^T [n][k]
    const float* bias = z == 0 ? bq : z == 1 ? bk : bv;
    __bf16* out = qkv + (size_t)z * NH * S_LEN * HD;

    const int tid = threadIdx.x, w = tid >> 6, l = tid & 63;
    const int lm = l & 15, q4 = l >> 4;
    const int bm = blockIdx.y, bn = blockIdx.x;
    const int wm = w >> 1, wn = w & 1;

    const int sm = (w << 4) + (l >> 2);
    const int skk = (l & 3) << 3;
    const __bf16* Ag = xb + (size_t)(bm * 128 + sm) * E_DIM + skk;
    const __bf16* Bg = Bt + (size_t)(bn * 128 + sm) * E_DIM + skk;
    unsigned short* AsW = As + (w << 9);
    unsigned short* BsW = Bs + (w << 9);

    f32x4_t acc[4][4];
#pragma unroll
    for (int i = 0; i < 4; i++)
#pragma unroll
        for (int j = 0; j < 4; j++) { acc[i][j].x = 0.f; acc[i][j].y = 0.f; acc[i][j].z = 0.f; acc[i][j].w = 0.f; }

    for (int k0 = 0; k0 < E_DIM; k0 += 32) {
        __syncthreads();
        GLD16(Ag + k0, AsW);
        GLD16(Ag + (size_t)64 * E_DIM + k0, AsW + 2048);
        GLD16(Bg + k0, BsW);
        GLD16(Bg + (size_t)64 * E_DIM + k0, BsW + 2048);
        __syncthreads();

        bf16x8_t af[4], bfr[4];
#pragma unroll
        for (int mt = 0; mt < 4; mt++)
            af[mt] = *(const bf16x8_t*)&As[(wm * 64 + mt * 16 + lm) * 32 + q4 * 8];
#pragma unroll
        for (int nt = 0; nt < 4; nt++)
            bfr[nt] = *(const bf16x8_t*)&Bs[(wn * 64 + nt * 16 + lm) * 32 + q4 * 8];
#pragma unroll
        for (int mt = 0; mt < 4; mt++)
#pragma unroll
            for (int nt = 0; nt < 4; nt++)
                acc[mt][nt] = __builtin_amdgcn_mfma_f32_16x16x32_bf16(af[mt], bfr[nt], acc[mt][nt], 0, 0, 0);
    }

    // C row s = bm*128 + wm*64 + mt*16 + q4*4 + i ; col n = bn*128 + wn*64 + nt*16 + lm
#pragma unroll
    for (int nt = 0; nt < 4; nt++) {
        const int n = bn * 128 + wn * 64 + nt * 16 + lm;
        const float bval = bias[n];
        const int h = n >> 6, d = n & 63;
        const int tile0 = bm * 2 + wm;          // s>>6
        if (z == 2) {
            // V A-op-native: key = mt*16 + q4*4 + i (local in tile)
            const int db = d >> 5, dl = d & 31;
#pragma unroll
            for (int mt = 0; mt < 4; mt++) {
                __bf16* ob = out + (((size_t)h * 32 + tile0) * 8 + db * 4 + mt) * 512
                                 + (dl + (q4 >> 1) * 32) * 8 + (q4 & 1) * 4;
                union { unsigned short s4[4]; uint2 u; } pk;
#pragma unroll
                for (int i = 0; i < 4; i++) pk.s4[i] = f2bf_bits(acc[mt][nt][i] + bval);
                *(uint2*)ob = pk.u;
            }
        } else {
            // Q/K op-native: s_local = mt*16 + q4*4 + i, rb = mt>>1
            const float scale = (z == 0) ? SM_SCALE : 1.0f;   // fold SM_SCALE into Q (exact: pow2)
            const int kc = d >> 4, khalf = (d >> 3) & 1, j = d & 7;
#pragma unroll
            for (int mt = 0; mt < 4; mt++) {
                __bf16* ob = out + (((size_t)h * 32 + tile0) * 8 + (mt >> 1) * 4 + kc) * 512
                                 + ((mt & 1) * 16 + q4 * 4 + khalf * 32) * 8 + j;
#pragma unroll
                for (int i = 0; i < 4; i++)
                    ob[i * 8] = (__bf16)((acc[mt][nt][i] + bval) * scale);
            }
        }
    }
}

// ------------------------------------------------------------- attention
// 32x32x16 MFMA. 4 waves = (row-half rh = w&1) x (key-half kh = w>>1).
// T15 att[2] double-pipeline: two live score tiles stA/stB (named vars,
// static indexing). Iteration s issues QK^T(s+1) (MFMA pipe) BEFORE the
// softmax-finish + PV of tile s (VALU pipe + MFMA) — the 4-deep serial QK
// chain hides under the previous tile's softmax. K/V staged 2 tiles ahead
// in a 3-buffer rotation, drained by the plain end-of-iteration
// __syncthreads (no manual vmcnt — R2 showed order-pinning regresses).
// Buffer use at iter s: write (s+2)%3, read K (s+1)%3, read V s%3 — disjoint.
// P fully in-register (T12 cvt_pk + permlane32_swap). Key-half partials
// combine linearly at end (no-max softmax, scores bounded).
__global__ __launch_bounds__(256, 2) void k_attn(
    const __bf16* __restrict__ Qf, const __bf16* __restrict__ Kf, const __bf16* __restrict__ Vf,
    __bf16* __restrict__ attn) {
    __shared__ __align__(16) unsigned short KVs[3][2][4096];  // [rot buf][K/V][8KB tile]

    // work-balanced swizzle: block b and b+256 land on the same CU (8-XCD
    // round-robin), pairing qt=16+(b>>4) with qt=15-(b>>4) -> 33 iter/CU.
    const int b = blockIdx.x;
    int qt, h;
    if (b < 256) { qt = 16 + (b >> 4); h = b & 15; }
    else         { qt = 15 - ((b - 256) >> 4); h = (b - 256) & 15; }

    const int tid = threadIdx.x, w = tid >> 6, l = tid & 63;
    const int rh = w & 1, kh = w >> 1;
    const int l31 = l & 31, lh = l >> 5;

    const __bf16* Qb = Qf + ((size_t)h * 32 + qt) * 4096;
    const __bf16* Kb = Kf + (size_t)h * 32 * 4096;
    const __bf16* Vb = Vf + (size_t)h * 32 * 4096;

    auto stage = [&](int t) {
        const int buf = t % 3;
        const __bf16* Kg = Kb + (size_t)t * 4096;
        const __bf16* Vg = Vb + (size_t)t * 4096;
        GLD16(Kg + (w << 9) + l * 8,       &KVs[buf][0][(w << 9) + l * 8]);
        GLD16(Kg + ((w + 4) << 9) + l * 8, &KVs[buf][0][((w + 4) << 9) + l * 8]);
        GLD16(Vg + (w << 9) + l * 8,       &KVs[buf][1][(w << 9) + l * 8]);
        GLD16(Vg + ((w + 4) << 9) + l * 8, &KVs[buf][1][((w + 4) << 9) + l * 8]);
    };

    // Q B-frags pinned (pre-scaled by SM_SCALE): rows rh*32..+31, 4 k-chunks
    bf16x8_t qf[4];
#pragma unroll
    for (int kc = 0; kc < 4; kc++)
        qf[kc] = *(const bf16x8_t*)(Qb + ((rh * 4 + kc) << 9) + l * 8);

    float lacc = 0.f;
    f32x16_t oacc[2];
#pragma unroll
    for (int db = 0; db < 2; db++)
#pragma unroll
        for (int r = 0; r < 16; r++) oacc[db][r] = 0.f;

    // S^T = K·Q^T for tile t : D[key = (reg&3)+8*(reg>>2)+4*lh][row = l31]
    auto qkt = [&](f32x16_t& dst, int t) {
        const int bbq = t % 3;
#pragma unroll
        for (int r = 0; r < 16; r++) dst[r] = 0.f;
        __builtin_amdgcn_s_setprio(1);
#pragma unroll
        for (int kc = 0; kc < 4; kc++) {
            bf16x8_t kf = *(const bf16x8_t*)&KVs[bbq][0][((kh * 4 + kc) << 9) + l * 8];
            dst = __builtin_amdgcn_mfma_f32_32x32x16_bf16(kf, qf[kc], dst, 0, 0, 0);
        }
        __builtin_amdgcn_s_setprio(0);
    };

    // softmax-finish + PV for tile s (scores in st)
    auto finish = [&](f32x16_t& st, int s) {
        const bool diag = (s == qt);
        if (diag && kh > rh) return;       // (rh=0,kh=1) diag block fully masked
        if (diag && kh == rh) {
#pragma unroll
            for (int r = 0; r < 16; r++) {
                const int keyl = (r & 3) + 8 * (r >> 2) + 4 * lh;
                st[r] = (keyl > l31) ? 0.f : __expf(st[r]);
            }
        } else {
#pragma unroll
            for (int r = 0; r < 16; r++) st[r] = __expf(st[r]);
        }
#pragma unroll
        for (int r = 0; r < 16; r++) lacc += st[r];
        const int bbv = s % 3;
        // O^T += V^T·P : A = V frags, B = P frags built fully in-register.
#pragma unroll
        for (int c = 0; c < 2; c++) {
            unsigned int v0 = cvt_pk_bf16(st[c * 8 + 0], st[c * 8 + 1]);
            unsigned int v1 = cvt_pk_bf16(st[c * 8 + 2], st[c * 8 + 3]);
            unsigned int v2 = cvt_pk_bf16(st[c * 8 + 4], st[c * 8 + 5]);
            unsigned int v3 = cvt_pk_bf16(st[c * 8 + 6], st[c * 8 + 7]);
            // a' = [a.lo | b.lo], b' = [a.hi | b.hi] across the lane halves
            asm("v_permlane32_swap_b32 %0, %1" : "+v"(v0), "+v"(v2));
            asm("v_permlane32_swap_b32 %0, %1" : "+v"(v1), "+v"(v3));
            union { unsigned int u4[4]; bf16x8_t v; } pku;
            pku.u4[0] = v0; pku.u4[1] = v1; pku.u4[2] = v2; pku.u4[3] = v3;
            __builtin_amdgcn_s_setprio(1);
#pragma unroll
            for (int db = 0; db < 2; db++) {
                bf16x8_t vf = *(const bf16x8_t*)&KVs[bbv][1][((db * 4 + kh * 2 + c) << 9) + l * 8];
                oacc[db] = __builtin_amdgcn_mfma_f32_32x32x16_bf16(vf, pku.v, oacc[db], 0, 0, 0);
            }
            __builtin_amdgcn_s_setprio(0);
        }
    };

    // prologue: tile 0 resident, tile 1 in flight, QK(0) computed
    stage(0);
    __syncthreads();                 // drains stage(0) (and qf loads)
    if (qt >= 1) stage(1);
    f32x16_t stA, stB;
    qkt(stA, 0);
    __syncthreads();                 // drains stage(1)

    int s = 0;
    while (true) {
        if (s + 2 <= qt) stage(s + 2);
        if (s < qt) qkt(stB, s + 1);
        finish(stA, s);
        __syncthreads();
        if (++s > qt) break;
        if (s + 2 <= qt) stage(s + 2);
        if (s < qt) qkt(stA, s + 1);
        finish(stB, s);
        __syncthreads();
        if (++s > qt) break;
    }

    // ---- key-half combine (linear: no-max softmax) ----
    float* Ex = (float*)KVs;                // [rh*64 + lane][34]: 32 O + lacc
    if (kh == 1) {
        float* e = Ex + (rh * 64 + l) * 34;
#pragma unroll
        for (int db = 0; db < 2; db++)
#pragma unroll
            for (int r = 0; r < 16; r++) e[db * 16 + r] = oacc[db][r];
        e[32] = lacc;
    }
    __syncthreads();
    if (kh == 0) {
        const float* e = Ex + (rh * 64 + l) * 34;
#pragma unroll
        for (int db = 0; db < 2; db++)
#pragma unroll
            for (int r = 0; r < 16; r++) oacc[db][r] += e[db * 16 + r];
        lacc += e[32];
        lacc += __shfl_xor(lacc, 32, 64);   // lanes l31 / l31+32 hold same row
        const float rl = 1.f / lacc;
        const int row = qt * 64 + rh * 32 + l31;
#pragma unroll
        for (int db = 0; db < 2; db++)
#pragma unroll
            for (int a = 0; a < 4; a++) {
                union { unsigned short s4[4]; uint2 u; } pk;
#pragma unroll
                for (int i = 0; i < 4; i++) pk.s4[i] = f2bf_bits(oacc[db][a * 4 + i] * rl);
                *(uint2*)(attn + (size_t)row * E_DIM + h * HD + db * 32 + a * 8 + lh * 4) = pk.u;
            }
    }
}

// --------------------------------------------------------- output projection
// 64x128 tile, double-buffered LDS staging (R1 form).
__global__ __launch_bounds__(256) void k_gemm_out(
    const __bf16* __restrict__ A, const __bf16* __restrict__ Bt,
    const float* __restrict__ bias, float* __restrict__ out) {
    __shared__ __align__(16) unsigned short As[2][64 * 32];
    __shared__ __align__(16) unsigned short Bs[2][128 * 32];

    const int tid = threadIdx.x, w = tid >> 6, l = tid & 63;
    const int lm = l & 15, q4 = l >> 4;
    const int bm = blockIdx.y, bn = blockIdx.x;
    const int wm = w >> 1, wn = w & 1;

    const int sm = (w << 4) + (l >> 2);
    const int skk = (l & 3) << 3;
    const __bf16* Ag = A + (size_t)(bm * 64 + sm) * E_DIM + skk;
    const __bf16* Bg = Bt + (size_t)(bn * 128 + sm) * E_DIM + skk;
    const int woff = w << 9;

    f32x4_t acc[2][4];
#pragma unroll
    for (int i = 0; i < 2; i++)
#pragma unroll
        for (int j = 0; j < 4; j++) { acc[i][j].x = 0.f; acc[i][j].y = 0.f; acc[i][j].z = 0.f; acc[i][j].w = 0.f; }

    GLD16(Ag, &As[0][woff]);
    GLD16(Bg, &Bs[0][woff]);
    GLD16(Bg + (size_t)64 * E_DIM, &Bs[0][woff + 2048]);
    __syncthreads();

    for (int s = 0; s < 32; s++) {
        const int bb = s & 1;
        if (s < 31) {
            const int k0 = (s + 1) * 32;
            GLD16(Ag + k0, &As[bb ^ 1][woff]);
            GLD16(Bg + k0, &Bs[bb ^ 1][woff]);
            GLD16(Bg + (size_t)64 * E_DIM + k0, &Bs[bb ^ 1][woff + 2048]);
        }

        bf16x8_t af[2], bfr[4];
#pragma unroll
        for (int mt = 0; mt < 2; mt++)
            af[mt] = *(const bf16x8_t*)&As[bb][(wm * 32 + mt * 16 + lm) * 32 + q4 * 8];
#pragma unroll
        for (int nt = 0; nt < 4; nt++)
            bfr[nt] = *(const bf16x8_t*)&Bs[bb][(wn * 64 + nt * 16 + lm) * 32 + q4 * 8];
#pragma unroll
        for (int mt = 0; mt < 2; mt++)
#pragma unroll
            for (int nt = 0; nt < 4; nt++)
                acc[mt][nt] = __builtin_amdgcn_mfma_f32_16x16x32_bf16(af[mt], bfr[nt], acc[mt][nt], 0, 0, 0);
        __syncthreads();
    }

#pragma unroll
    for (int nt = 0; nt < 4; nt++) {
        const int n = bn * 128 + wn * 64 + nt * 16 + lm;
        const float bval = bias[n];
#pragma unroll
        for (int mt = 0; mt < 2; mt++) {
            const int r0 = bm * 64 + wm * 32 + mt * 16 + q4 * 4;
#pragma unroll
            for (int i = 0; i < 4; i++)
                out[(size_t)(r0 + i) * E_DIM + n] = acc[mt][nt][i] + bval;
        }
    }
}

extern "C" void kernel_launch(void* const* d_in, const int* in_sizes, int n_in,
                              void* d_out, int out_size, void* d_ws, size_t ws_size,
                              hipStream_t stream) {
    const float* x  = (const float*)d_in[0];
    const float* Wq = (const float*)d_in[1];
    const float* bq = (const float*)d_in[2];
    const float* Wk = (const float*)d_in[3];
    const float* bk = (const float*)d_in[4];
    const float* Wv = (const float*)d_in[5];
    const float* bv = (const float*)d_in[6];
    const float* Wo = (const float*)d_in[7];
    const float* bo = (const float*)d_in[8];
    float* out = (float*)d_out;

    char* ws = (char*)d_ws;
    __bf16* xb   = (__bf16*)(ws);                        // 4 MB  x bf16 [S][E]
    __bf16* wt   = (__bf16*)(ws + ((size_t)4  << 20));   // 4x2MB [Wq^T,Wk^T,Wv^T,Wo^T] bf16
    __bf16* qkv  = (__bf16*)(ws + ((size_t)12 << 20));   // op-native Qf,Kf,Vf (4MB each)
    __bf16* attn = (__bf16*)(ws + ((size_t)24 << 20));   // 4 MB  [S][E] bf16

    k_prep<<<dim3(32, 32, 6), dim3(32, 8), 0, stream>>>(x, Wq, Wk, Wv, Wo, xb, wt);
    k_gemm_qkv<<<dim3(E_DIM / 128, S_LEN / 128, 3), 256, 0, stream>>>(xb, wt, bq, bk, bv, qkv);
    k_attn<<<dim3(512), 256, 0, stream>>>(
        qkv, qkv + (size_t)NH * S_LEN * HD, qkv + (size_t)2 * NH * S_LEN * HD, attn);
    k_gemm_out<<<dim3(E_DIM / 128, S_LEN / 64), 256, 0, stream>>>(
        attn, wt + (size_t)3 * E_DIM * E_DIM, bo, out);
}

// Round 4
// 146.869 us; speedup vs baseline: 1.0857x; 1.0348x over previous
//
#include <hip/hip_runtime.h>
#include <hip/hip_bf16.h>

// Problem constants (B=1)
#define S_LEN 2048
#define E_DIM 1024
#define NH    16
#define HD    64
#define SM_SCALE 0.5f

typedef short bf16x8_t  __attribute__((ext_vector_type(8)));    // 8 bf16 = 4 VGPRs
typedef float f32x4_t   __attribute__((ext_vector_type(4)));
typedef float f32x16_t  __attribute__((ext_vector_type(16)));
typedef __bf16 bf16x4_t __attribute__((ext_vector_type(4)));

static __device__ __forceinline__ unsigned short f2bf_bits(float f) {
    return __builtin_bit_cast(unsigned short, (__bf16)f);
}

// v_cvt_pk_bf16_f32: dst.lo = bf16(lo), dst.hi = bf16(hi)  (RNE, same as (__bf16) cast)
static __device__ __forceinline__ unsigned int cvt_pk_bf16(float lo, float hi) {
    unsigned int r;
    asm("v_cvt_pk_bf16_f32 %0, %1, %2" : "=v"(r) : "v"(lo), "v"(hi));
    return r;
}

// async global->LDS, 16B per lane, dest = wave-uniform base + lane*16
#define GLD16(gp, lp) __builtin_amdgcn_global_load_lds(                       \
    (const __attribute__((address_space(1))) void*)(gp),                      \
    (__attribute__((address_space(3))) void*)(lp), 16, 0, 0)

// -------------------------------------------- merged prep: W^T + x->bf16
__global__ void k_prep(const float* __restrict__ x,
                       const float* __restrict__ Wq, const float* __restrict__ Wk,
                       const float* __restrict__ Wv, const float* __restrict__ Wo,
                       __bf16* __restrict__ xb, __bf16* __restrict__ wt) {
    const int z = blockIdx.z;
    if (z < 4) {
        __shared__ float tile[32][33];
        const float* W = z == 0 ? Wq : z == 1 ? Wk : z == 2 ? Wv : Wo;
        __bf16* o = wt + (size_t)z * E_DIM * E_DIM;
        const int tx = threadIdx.x, ty = threadIdx.y;
        const int bx = blockIdx.x * 32, by = blockIdx.y * 32;
#pragma unroll
        for (int j = 0; j < 32; j += 8)
            tile[ty + j][tx] = W[(size_t)(by + ty + j) * E_DIM + bx + tx];
        __syncthreads();
#pragma unroll
        for (int j = 0; j < 32; j += 8)
            o[(size_t)(bx + ty + j) * E_DIM + by + tx] = (__bf16)tile[tx][ty + j];
    } else {
        const int bid = (z - 4) * 1024 + blockIdx.y * 32 + blockIdx.x;
        const int tid = threadIdx.y * 32 + threadIdx.x;
        const int i = bid * 256 + tid;
        const float4 v = ((const float4*)x)[i];
        bf16x4_t o4;
        o4.x = (__bf16)v.x; o4.y = (__bf16)v.y; o4.z = (__bf16)v.z; o4.w = (__bf16)v.w;
        ((bf16x4_t*)xb)[i] = o4;
    }
}

// ------------------------------------------------------- QKV projection GEMM
// 128x64 tile, BK=32, two-barrier GLD16 staging (R1 inner-loop form — manual
// vmcnt rings regressed, m141). Tile shrunk from 128x128 so the grid is
// 16x16x3 = 768 blocks = exactly 3.0 blocks/CU (was 384 = 1.5/CU: half the
// CUs ran 2 serial tiles -> ~33% idle). 12KB LDS / ~100 VGPR also lets 3-4
// blocks co-reside, overlapping the per-step barrier drain across blocks.
// Epilogue scatters into 32x32x16-MFMA operand-native layout (unchanged):
//   Q (B-op): [h][qt][rb2][kc4][lane64][j8]  rb=(s&63)>>5, lane=(s&31)+((d>>3)&1)*32, kc=d>>4, j=d&7
//   K (A-op): same index function as Q
//   V (A-op, V^T): [h][kt][db2][kc4][lane64][j8] db=d>>5, lane=(d&31)+((key>>3)&1)*32, kc=(key&63)>>4, j=key&7
__global__ __launch_bounds__(256) void k_gemm_qkv(
    const __bf16* __restrict__ xb, const __bf16* __restrict__ wt,
    const float* __restrict__ bq, const float* __restrict__ bk, const float* __restrict__ bv,
    __bf16* __restrict__ qkv) {
    __shared__ __align__(16) unsigned short As[128 * 32];   // 8 KB
    __shared__ __align__(16) unsigned short Bs[64 * 32];    // 4 KB

    const int z = blockIdx.z;
    const __bf16* Bt = wt + (size_t)z * E_DIM * E_DIM;      // W^T [n][k]
    const float* bias = z == 0 ? bq : z == 1 ? bk : bv;
    __bf16* out = qkv + (size_t)z * NH * S_LEN * HD;

    const int tid = threadIdx.x, w = tid >> 6, l = tid & 63;
    const int lm = l & 15, q4 = l >> 4;
    const int bm = blockIdx.y, bn = blockIdx.x;
    const int wm = w >> 1, wn = w & 1;                      // 2x2 waves, 64x32 each

    const int sm = (w << 4) + (l >> 2);                     // staging row 0..63
    const int skk = (l & 3) << 3;
    const __bf16* Ag = xb + (size_t)(bm * 128 + sm) * E_DIM + skk;
    const __bf16* Bg = Bt + (size_t)(bn * 64 + sm) * E_DIM + skk;
    unsigned short* AsW = As + (w << 9);
    unsigned short* BsW = Bs + (w << 9);

    f32x4_t acc[4][2];
#pragma unroll
    for (int i = 0; i < 4; i++)
#pragma unroll
        for (int j = 0; j < 2; j++) { acc[i][j].x = 0.f; acc[i][j].y = 0.f; acc[i][j].z = 0.f; acc[i][j].w = 0.f; }

    for (int k0 = 0; k0 < E_DIM; k0 += 32) {
        __syncthreads();
        GLD16(Ag + k0, AsW);
        GLD16(Ag + (size_t)64 * E_DIM + k0, AsW + 2048);
        GLD16(Bg + k0, BsW);
        __syncthreads();

        bf16x8_t af[4], bfr[2];
#pragma unroll
        for (int mt = 0; mt < 4; mt++)
            af[mt] = *(const bf16x8_t*)&As[(wm * 64 + mt * 16 + lm) * 32 + q4 * 8];
#pragma unroll
        for (int nt = 0; nt < 2; nt++)
            bfr[nt] = *(const bf16x8_t*)&Bs[(wn * 32 + nt * 16 + lm) * 32 + q4 * 8];
#pragma unroll
        for (int mt = 0; mt < 4; mt++)
#pragma unroll
            for (int nt = 0; nt < 2; nt++)
                acc[mt][nt] = __builtin_amdgcn_mfma_f32_16x16x32_bf16(af[mt], bfr[nt], acc[mt][nt], 0, 0, 0);
    }

    // C row s = bm*128 + wm*64 + mt*16 + q4*4 + i ; col n = bn*64 + wn*32 + nt*16 + lm
#pragma unroll
    for (int nt = 0; nt < 2; nt++) {
        const int n = bn * 64 + wn * 32 + nt * 16 + lm;
        const float bval = bias[n];
        const int h = n >> 6, d = n & 63;
        const int tile0 = bm * 2 + wm;          // s>>6
        if (z == 2) {
            // V A-op-native: key = mt*16 + q4*4 + i (local in tile)
            const int db = d >> 5, dl = d & 31;
#pragma unroll
            for (int mt = 0; mt < 4; mt++) {
                __bf16* ob = out + (((size_t)h * 32 + tile0) * 8 + db * 4 + mt) * 512
                                 + (dl + (q4 >> 1) * 32) * 8 + (q4 & 1) * 4;
                union { unsigned short s4[4]; uint2 u; } pk;
#pragma unroll
                for (int i = 0; i < 4; i++) pk.s4[i] = f2bf_bits(acc[mt][nt][i] + bval);
                *(uint2*)ob = pk.u;
            }
        } else {
            // Q/K op-native: s_local = mt*16 + q4*4 + i, rb = mt>>1
            const float scale = (z == 0) ? SM_SCALE : 1.0f;   // fold SM_SCALE into Q (exact: pow2)
            const int kc = d >> 4, khalf = (d >> 3) & 1, j = d & 7;
#pragma unroll
            for (int mt = 0; mt < 4; mt++) {
                __bf16* ob = out + (((size_t)h * 32 + tile0) * 8 + (mt >> 1) * 4 + kc) * 512
                                 + ((mt & 1) * 16 + q4 * 4 + khalf * 32) * 8 + j;
#pragma unroll
                for (int i = 0; i < 4; i++)
                    ob[i * 8] = (__bf16)((acc[mt][nt][i] + bval) * scale);
            }
        }
    }
}

// ------------------------------------------------------------- attention
// R1 form (measured best). 32x32x16 MFMA. 4 waves = (row-half rh = w&1) x
// (key-half kh = w>>1). Wave (rh,kh): S^T(32k x 32r) = K_kh · Q_rh^T in 4
// MFMA, O^T(64d x 32r) += V^T·P in 4 MFMA. P fully in-register (T12 cvt_pk +
// permlane32_swap). Key-half partials combine linearly at end (no-max
// softmax, scores bounded). K/V tiles double-buffered via GLD16; plain
// __syncthreads pipeline (R2 counted-vmcnt and R3 att[2] both regressed).
__global__ __launch_bounds__(256, 2) void k_attn(
    const __bf16* __restrict__ Qf, const __bf16* __restrict__ Kf, const __bf16* __restrict__ Vf,
    __bf16* __restrict__ attn) {
    __shared__ __align__(16) unsigned short KVs[2][2][4096];  // [buf][K/V][8KB tile]

    // work-balanced swizzle: long q-tiles dispatched first
    const int b = blockIdx.x;
    int qt, h;
    if (b < 256) { qt = 16 + (b >> 4); h = b & 15; }
    else         { qt = 15 - ((b - 256) >> 4); h = (b - 256) & 15; }

    const int tid = threadIdx.x, w = tid >> 6, l = tid & 63;
    const int rh = w & 1, kh = w >> 1;
    const int l31 = l & 31, lh = l >> 5;

    const __bf16* Qb = Qf + ((size_t)h * 32 + qt) * 4096;
    const __bf16* Kb = Kf + (size_t)h * 32 * 4096;
    const __bf16* Vb = Vf + (size_t)h * 32 * 4096;

    // Q B-frags pinned (pre-scaled by SM_SCALE): rows rh*32..+31, 4 k-chunks
    bf16x8_t qf[4];
#pragma unroll
    for (int kc = 0; kc < 4; kc++)
        qf[kc] = *(const bf16x8_t*)(Qb + ((rh * 4 + kc) << 9) + l * 8);

    float lacc = 0.f;
    f32x16_t oacc[2];
#pragma unroll
    for (int db = 0; db < 2; db++)
#pragma unroll
        for (int r = 0; r < 16; r++) oacc[db][r] = 0.f;

    // prologue: stage tile 0 into buf 0 (wave w: chunks w, w+4 of K and V)
    GLD16(Kb + (w << 9) + l * 8,       &KVs[0][0][(w << 9) + l * 8]);
    GLD16(Kb + ((w + 4) << 9) + l * 8, &KVs[0][0][((w + 4) << 9) + l * 8]);
    GLD16(Vb + (w << 9) + l * 8,       &KVs[0][1][(w << 9) + l * 8]);
    GLD16(Vb + ((w + 4) << 9) + l * 8, &KVs[0][1][((w + 4) << 9) + l * 8]);
    __syncthreads();

    for (int s = 0; s <= qt; s++) {
        const int bb = s & 1;
        if (s < qt) {   // prefetch next tile into the other buffer
            const __bf16* Kg = Kb + (size_t)(s + 1) * 4096;
            const __bf16* Vg = Vb + (size_t)(s + 1) * 4096;
            GLD16(Kg + (w << 9) + l * 8,       &KVs[bb ^ 1][0][(w << 9) + l * 8]);
            GLD16(Kg + ((w + 4) << 9) + l * 8, &KVs[bb ^ 1][0][((w + 4) << 9) + l * 8]);
            GLD16(Vg + (w << 9) + l * 8,       &KVs[bb ^ 1][1][(w << 9) + l * 8]);
            GLD16(Vg + ((w + 4) << 9) + l * 8, &KVs[bb ^ 1][1][((w + 4) << 9) + l * 8]);
        }

        const bool diag = (s == qt);
        if (!(diag && kh > rh)) {          // (rh=0,kh=1) diag block fully masked
            // S^T = K·Q^T : D[key = (reg&3)+8*(reg>>2)+4*lh][row = l31]
            f32x16_t st;
#pragma unroll
            for (int r = 0; r < 16; r++) st[r] = 0.f;
            __builtin_amdgcn_s_setprio(1);
#pragma unroll
            for (int kc = 0; kc < 4; kc++) {
                bf16x8_t kf = *(const bf16x8_t*)&KVs[bb][0][((kh * 4 + kc) << 9) + l * 8];
                st = __builtin_amdgcn_mfma_f32_32x32x16_bf16(kf, qf[kc], st, 0, 0, 0);
            }
            __builtin_amdgcn_s_setprio(0);
            // exp (+ causal mask only on the diagonal kh==rh block)
            if (diag && kh == rh) {
#pragma unroll
                for (int r = 0; r < 16; r++) {
                    const int keyl = (r & 3) + 8 * (r >> 2) + 4 * lh;
                    st[r] = (keyl > l31) ? 0.f : __expf(st[r]);
                }
            } else {
#pragma unroll
                for (int r = 0; r < 16; r++) st[r] = __expf(st[r]);
            }
#pragma unroll
            for (int r = 0; r < 16; r++) lacc += st[r];
            // O^T += V^T·P : A = V frags, B = P frags built fully in-register.
            // c covers keys kh*32 + c*16 + {0..15}; st regs c*8.. c*8+7 hold them.
#pragma unroll
            for (int c = 0; c < 2; c++) {
                unsigned int v0 = cvt_pk_bf16(st[c * 8 + 0], st[c * 8 + 1]);
                unsigned int v1 = cvt_pk_bf16(st[c * 8 + 2], st[c * 8 + 3]);
                unsigned int v2 = cvt_pk_bf16(st[c * 8 + 4], st[c * 8 + 5]);
                unsigned int v3 = cvt_pk_bf16(st[c * 8 + 6], st[c * 8 + 7]);
                // a' = [a.lo | b.lo], b' = [a.hi | b.hi] across the lane<32/>=32 halves
                asm("v_permlane32_swap_b32 %0, %1" : "+v"(v0), "+v"(v2));
                asm("v_permlane32_swap_b32 %0, %1" : "+v"(v1), "+v"(v3));
                union { unsigned int u4[4]; bf16x8_t v; } pku;
                pku.u4[0] = v0; pku.u4[1] = v1; pku.u4[2] = v2; pku.u4[3] = v3;
                __builtin_amdgcn_s_setprio(1);
#pragma unroll
                for (int db = 0; db < 2; db++) {
                    bf16x8_t vf = *(const bf16x8_t*)&KVs[bb][1][((db * 4 + kh * 2 + c) << 9) + l * 8];
                    oacc[db] = __builtin_amdgcn_mfma_f32_32x32x16_bf16(vf, pku.v, oacc[db], 0, 0, 0);
                }
                __builtin_amdgcn_s_setprio(0);
            }
        }
        __syncthreads();   // reads of buf bb done; prefetch of bb^1 landed
    }

    // ---- key-half combine (linear: no-max softmax) ----
    __syncthreads();                        // KVs reusable as exchange space
    float* Ex = (float*)KVs;                // [rh*64 + lane][34]: 32 O + lacc
    if (kh == 1) {
        float* e = Ex + (rh * 64 + l) * 34;
#pragma unroll
        for (int db = 0; db < 2; db++)
#pragma unroll
            for (int r = 0; r < 16; r++) e[db * 16 + r] = oacc[db][r];
        e[32] = lacc;
    }
    __syncthreads();
    if (kh == 0) {
        const float* e = Ex + (rh * 64 + l) * 34;
#pragma unroll
        for (int db = 0; db < 2; db++)
#pragma unroll
            for (int r = 0; r < 16; r++) oacc[db][r] += e[db * 16 + r];
        lacc += e[32];
        lacc += __shfl_xor(lacc, 32, 64);   // lanes l31 / l31+32 hold same row
        const float rl = 1.f / lacc;
        const int row = qt * 64 + rh * 32 + l31;
#pragma unroll
        for (int db = 0; db < 2; db++)
#pragma unroll
            for (int a = 0; a < 4; a++) {
                union { unsigned short s4[4]; uint2 u; } pk;
#pragma unroll
                for (int i = 0; i < 4; i++) pk.s4[i] = f2bf_bits(oacc[db][a * 4 + i] * rl);
                *(uint2*)(attn + (size_t)row * E_DIM + h * HD + db * 32 + a * 8 + lh * 4) = pk.u;
            }
    }
}

// --------------------------------------------------------- output projection
// 64x128 tile, double-buffered LDS staging (R1 form).
__global__ __launch_bounds__(256) void k_gemm_out(
    const __bf16* __restrict__ A, const __bf16* __restrict__ Bt,
    const float* __restrict__ bias, float* __restrict__ out) {
    __shared__ __align__(16) unsigned short As[2][64 * 32];
    __shared__ __align__(16) unsigned short Bs[2][128 * 32];

    const int tid = threadIdx.x, w = tid >> 6, l = tid & 63;
    const int lm = l & 15, q4 = l >> 4;
    const int bm = blockIdx.y, bn = blockIdx.x;
    const int wm = w >> 1, wn = w & 1;

    const int sm = (w << 4) + (l >> 2);
    const int skk = (l & 3) << 3;
    const __bf16* Ag = A + (size_t)(bm * 64 + sm) * E_DIM + skk;
    const __bf16* Bg = Bt + (size_t)(bn * 128 + sm) * E_DIM + skk;
    const int woff = w << 9;

    f32x4_t acc[2][4];
#pragma unroll
    for (int i = 0; i < 2; i++)
#pragma unroll
        for (int j = 0; j < 4; j++) { acc[i][j].x = 0.f; acc[i][j].y = 0.f; acc[i][j].z = 0.f; acc[i][j].w = 0.f; }

    GLD16(Ag, &As[0][woff]);
    GLD16(Bg, &Bs[0][woff]);
    GLD16(Bg + (size_t)64 * E_DIM, &Bs[0][woff + 2048]);
    __syncthreads();

    for (int s = 0; s < 32; s++) {
        const int bb = s & 1;
        if (s < 31) {
            const int k0 = (s + 1) * 32;
            GLD16(Ag + k0, &As[bb ^ 1][woff]);
            GLD16(Bg + k0, &Bs[bb ^ 1][woff]);
            GLD16(Bg + (size_t)64 * E_DIM + k0, &Bs[bb ^ 1][woff + 2048]);
        }

        bf16x8_t af[2], bfr[4];
#pragma unroll
        for (int mt = 0; mt < 2; mt++)
            af[mt] = *(const bf16x8_t*)&As[bb][(wm * 32 + mt * 16 + lm) * 32 + q4 * 8];
#pragma unroll
        for (int nt = 0; nt < 4; nt++)
            bfr[nt] = *(const bf16x8_t*)&Bs[bb][(wn * 64 + nt * 16 + lm) * 32 + q4 * 8];
#pragma unroll
        for (int mt = 0; mt < 2; mt++)
#pragma unroll
            for (int nt = 0; nt < 4; nt++)
                acc[mt][nt] = __builtin_amdgcn_mfma_f32_16x16x32_bf16(af[mt], bfr[nt], acc[mt][nt], 0, 0, 0);
        __syncthreads();
    }

#pragma unroll
    for (int nt = 0; nt < 4; nt++) {
        const int n = bn * 128 + wn * 64 + nt * 16 + lm;
        const float bval = bias[n];
#pragma unroll
        for (int mt = 0; mt < 2; mt++) {
            const int r0 = bm * 64 + wm * 32 + mt * 16 + q4 * 4;
#pragma unroll
            for (int i = 0; i < 4; i++)
                out[(size_t)(r0 + i) * E_DIM + n] = acc[mt][nt][i] + bval;
        }
    }
}

extern "C" void kernel_launch(void* const* d_in, const int* in_sizes, int n_in,
                              void* d_out, int out_size, void* d_ws, size_t ws_size,
                              hipStream_t stream) {
    const float* x  = (const float*)d_in[0];
    const float* Wq = (const float*)d_in[1];
    const float* bq = (const float*)d_in[2];
    const float* Wk = (const float*)d_in[3];
    const float* bk = (const float*)d_in[4];
    const float* Wv = (const float*)d_in[5];
    const float* bv = (const float*)d_in[6];
    const float* Wo = (const float*)d_in[7];
    const float* bo = (const float*)d_in[8];
    float* out = (float*)d_out;

    char* ws = (char*)d_ws;
    __bf16* xb   = (__bf16*)(ws);                        // 4 MB  x bf16 [S][E]
    __bf16* wt   = (__bf16*)(ws + ((size_t)4  << 20));   // 4x2MB [Wq^T,Wk^T,Wv^T,Wo^T] bf16
    __bf16* qkv  = (__bf16*)(ws + ((size_t)12 << 20));   // op-native Qf,Kf,Vf (4MB each)
    __bf16* attn = (__bf16*)(ws + ((size_t)24 << 20));   // 4 MB  [S][E] bf16

    k_prep<<<dim3(32, 32, 6), dim3(32, 8), 0, stream>>>(x, Wq, Wk, Wv, Wo, xb, wt);
    k_gemm_qkv<<<dim3(E_DIM / 64, S_LEN / 128, 3), 256, 0, stream>>>(xb, wt, bq, bk, bv, qkv);
    k_attn<<<dim3(512), 256, 0, stream>>>(
        qkv, qkv + (size_t)NH * S_LEN * HD, qkv + (size_t)2 * NH * S_LEN * HD, attn);
    k_gemm_out<<<dim3(E_DIM / 128, S_LEN / 64), 256, 0, stream>>>(
        attn, wt + (size_t)3 * E_DIM * E_DIM, bo, out);
}

// Round 5
// 145.966 us; speedup vs baseline: 1.0924x; 1.0062x over previous
//
#include <hip/hip_runtime.h>
#include <hip/hip_bf16.h>

// Problem constants (B=1)
#define S_LEN 2048
#define E_DIM 1024
#define NH    16
#define HD    64
#define SM_SCALE 0.5f

typedef short bf16x8_t  __attribute__((ext_vector_type(8)));    // 8 bf16 = 4 VGPRs
typedef float f32x4_t   __attribute__((ext_vector_type(4)));
typedef float f32x16_t  __attribute__((ext_vector_type(16)));
typedef __bf16 bf16x4_t __attribute__((ext_vector_type(4)));

static __device__ __forceinline__ unsigned short f2bf_bits(float f) {
    return __builtin_bit_cast(unsigned short, (__bf16)f);
}

// v_cvt_pk_bf16_f32: dst.lo = bf16(lo), dst.hi = bf16(hi)  (RNE, same as (__bf16) cast)
static __device__ __forceinline__ unsigned int cvt_pk_bf16(float lo, float hi) {
    unsigned int r;
    asm("v_cvt_pk_bf16_f32 %0, %1, %2" : "=v"(r) : "v"(lo), "v"(hi));
    return r;
}

// async global->LDS, 16B per lane, dest = wave-uniform base + lane*16
#define GLD16(gp, lp) __builtin_amdgcn_global_load_lds(                       \
    (const __attribute__((address_space(1))) void*)(gp),                      \
    (__attribute__((address_space(3))) void*)(lp), 16, 0, 0)

// -------------------------------------------- merged prep: W^T + x->bf16
__global__ void k_prep(const float* __restrict__ x,
                       const float* __restrict__ Wq, const float* __restrict__ Wk,
                       const float* __restrict__ Wv, const float* __restrict__ Wo,
                       __bf16* __restrict__ xb, __bf16* __restrict__ wt) {
    const int z = blockIdx.z;
    if (z < 4) {
        __shared__ float tile[32][33];
        const float* W = z == 0 ? Wq : z == 1 ? Wk : z == 2 ? Wv : Wo;
        __bf16* o = wt + (size_t)z * E_DIM * E_DIM;
        const int tx = threadIdx.x, ty = threadIdx.y;
        const int bx = blockIdx.x * 32, by = blockIdx.y * 32;
#pragma unroll
        for (int j = 0; j < 32; j += 8)
            tile[ty + j][tx] = W[(size_t)(by + ty + j) * E_DIM + bx + tx];
        __syncthreads();
#pragma unroll
        for (int j = 0; j < 32; j += 8)
            o[(size_t)(bx + ty + j) * E_DIM + by + tx] = (__bf16)tile[tx][ty + j];
    } else {
        const int bid = (z - 4) * 1024 + blockIdx.y * 32 + blockIdx.x;
        const int tid = threadIdx.y * 32 + threadIdx.x;
        const int i = bid * 256 + tid;
        const float4 v = ((const float4*)x)[i];
        bf16x4_t o4;
        o4.x = (__bf16)v.x; o4.y = (__bf16)v.y; o4.z = (__bf16)v.z; o4.w = (__bf16)v.w;
        ((bf16x4_t*)xb)[i] = o4;
    }
}

// ------------------------------------------------------- QKV projection GEMM
// 128x128 tile, BK=32 (R1 form, best measured — R4's 128x64 was neutral).
// Epilogue scatters into 32x32x16-MFMA operand-native layout:
//   Q (B-op): [h][qt][rb2][kc4][lane64][j8]  rb=(s&63)>>5, lane=(s&31)+((d>>3)&1)*32, kc=d>>4, j=d&7
//   K (A-op): same index function as Q
//   V (A-op, V^T): [h][kt][db2][kc4][lane64][j8] db=d>>5, lane=(d&31)+((key>>3)&1)*32, kc=(key&63)>>4, j=key&7
__global__ __launch_bounds__(256) void k_gemm_qkv(
    const __bf16* __restrict__ xb, const __bf16* __restrict__ wt,
    const float* __restrict__ bq, const float* __restrict__ bk, const float* __restrict__ bv,
    __bf16* __restrict__ qkv) {
    __shared__ __align__(16) unsigned short As[128 * 32];
    __shared__ __align__(16) unsigned short Bs[128 * 32];

    const int z = blockIdx.z;
    const __bf16* Bt = wt + (size_t)z * E_DIM * E_DIM;      // W^T [n][k]
    const float* bias = z == 0 ? bq : z == 1 ? bk : bv;
    __bf16* out = qkv + (size_t)z * NH * S_LEN * HD;

    const int tid = threadIdx.x, w = tid >> 6, l = tid & 63;
    const int lm = l & 15, q4 = l >> 4;
    const int bm = blockIdx.y, bn = blockIdx.x;
    const int wm = w >> 1, wn = w & 1;

    const int sm = (w << 4) + (l >> 2);
    const int skk = (l & 3) << 3;
    const __bf16* Ag = xb + (size_t)(bm * 128 + sm) * E_DIM + skk;
    const __bf16* Bg = Bt + (size_t)(bn * 128 + sm) * E_DIM + skk;
    unsigned short* AsW = As + (w << 9);
    unsigned short* BsW = Bs + (w << 9);

    f32x4_t acc[4][4];
#pragma unroll
    for (int i = 0; i < 4; i++)
#pragma unroll
        for (int j = 0; j < 4; j++) { acc[i][j].x = 0.f; acc[i][j].y = 0.f; acc[i][j].z = 0.f; acc[i][j].w = 0.f; }

    for (int k0 = 0; k0 < E_DIM; k0 += 32) {
        __syncthreads();
        GLD16(Ag + k0, AsW);
        GLD16(Ag + (size_t)64 * E_DIM + k0, AsW + 2048);
        GLD16(Bg + k0, BsW);
        GLD16(Bg + (size_t)64 * E_DIM + k0, BsW + 2048);
        __syncthreads();

        bf16x8_t af[4], bfr[4];
#pragma unroll
        for (int mt = 0; mt < 4; mt++)
            af[mt] = *(const bf16x8_t*)&As[(wm * 64 + mt * 16 + lm) * 32 + q4 * 8];
#pragma unroll
        for (int nt = 0; nt < 4; nt++)
            bfr[nt] = *(const bf16x8_t*)&Bs[(wn * 64 + nt * 16 + lm) * 32 + q4 * 8];
#pragma unroll
        for (int mt = 0; mt < 4; mt++)
#pragma unroll
            for (int nt = 0; nt < 4; nt++)
                acc[mt][nt] = __builtin_amdgcn_mfma_f32_16x16x32_bf16(af[mt], bfr[nt], acc[mt][nt], 0, 0, 0);
    }

    // C row s = bm*128 + wm*64 + mt*16 + q4*4 + i ; col n = bn*128 + wn*64 + nt*16 + lm
#pragma unroll
    for (int nt = 0; nt < 4; nt++) {
        const int n = bn * 128 + wn * 64 + nt * 16 + lm;
        const float bval = bias[n];
        const int h = n >> 6, d = n & 63;
        const int tile0 = bm * 2 + wm;          // s>>6
        if (z == 2) {
            // V A-op-native: key = mt*16 + q4*4 + i (local in tile)
            const int db = d >> 5, dl = d & 31;
#pragma unroll
            for (int mt = 0; mt < 4; mt++) {
                __bf16* ob = out + (((size_t)h * 32 + tile0) * 8 + db * 4 + mt) * 512
                                 + (dl + (q4 >> 1) * 32) * 8 + (q4 & 1) * 4;
                union { unsigned short s4[4]; uint2 u; } pk;
#pragma unroll
                for (int i = 0; i < 4; i++) pk.s4[i] = f2bf_bits(acc[mt][nt][i] + bval);
                *(uint2*)ob = pk.u;
            }
        } else {
            // Q/K op-native: s_local = mt*16 + q4*4 + i, rb = mt>>1
            const float scale = (z == 0) ? SM_SCALE : 1.0f;   // fold SM_SCALE into Q (exact: pow2)
            const int kc = d >> 4, khalf = (d >> 3) & 1, j = d & 7;
#pragma unroll
            for (int mt = 0; mt < 4; mt++) {
                __bf16* ob = out + (((size_t)h * 32 + tile0) * 8 + (mt >> 1) * 4 + kc) * 512
                                 + ((mt & 1) * 16 + q4 * 4 + khalf * 32) * 8 + j;
#pragma unroll
                for (int i = 0; i < 4; i++)
                    ob[i * 8] = (__bf16)((acc[mt][nt][i] + bval) * scale);
            }
        }
    }
}

// ------------------------------------------------------------- attention
// KVBLK=128: each K/V staging tile covers 128 keys = TWO consecutive 64-key
// op-native groups (contiguous in memory, so GLD16 staging is unchanged in
// spirit: 16 chunks of 1KB per operand). 4 waves = (row-half rh = w&1) x
// (key-half kh = w>>1); wave (rh,kh) handles q-rows [qt*64+rh*32,+32) x keys
// [t*128+kh*64,+64) = key group kh of the tile, as two 32-key sub-tiles.
// Benefits vs KVBLK=64: barrier/drain count halves (33 -> 17 iter/CU) and the
// QK^T serial 4-chain becomes two INDEPENDENT chains that interleave in the
// MFMA pipe. Causal mask generalizes: sub-tile at key base B is skipped iff
// B > rowmin+31, triangular iff B+31 > rowmin (off = rowmin-B), else plain.
// P fully in-register (T12 cvt_pk + permlane32_swap). Key-half partials
// combine linearly at end (no-max softmax, scores bounded). Plain
// __syncthreads double-buffer (R2 counted-vmcnt / R3 att[2] both regressed).
__global__ __launch_bounds__(256, 2) void k_attn(
    const __bf16* __restrict__ Qf, const __bf16* __restrict__ Kf, const __bf16* __restrict__ Vf,
    __bf16* __restrict__ attn) {
    __shared__ __align__(16) unsigned short KVs[2][2][8192];  // [buf][K/V][16KB = 128 keys]

    // work-balanced swizzle: long q-tiles dispatched first
    const int b = blockIdx.x;
    int qt, h;
    if (b < 256) { qt = 16 + (b >> 4); h = b & 15; }
    else         { qt = 15 - ((b - 256) >> 4); h = (b - 256) & 15; }

    const int tid = threadIdx.x, w = tid >> 6, l = tid & 63;
    const int rh = w & 1, kh = w >> 1;
    const int l31 = l & 31, lh = l >> 5;

    const __bf16* Qb = Qf + ((size_t)h * 32 + qt) * 4096;
    const __bf16* Kb = Kf + (size_t)h * 32 * 4096;
    const __bf16* Vb = Vf + (size_t)h * 32 * 4096;

    // stage 128-key tile t (16KB K + 16KB V); wave w covers chunks w+4i
    auto stage = [&](int t, int buf) {
        const __bf16* Kg = Kb + (size_t)t * 8192;
        const __bf16* Vg = Vb + (size_t)t * 8192;
#pragma unroll
        for (int i = 0; i < 4; i++) {
            const int ch = (w + i * 4) << 9;
            GLD16(Kg + ch + l * 8, &KVs[buf][0][ch + l * 8]);
            GLD16(Vg + ch + l * 8, &KVs[buf][1][ch + l * 8]);
        }
    };

    // Q B-frags pinned (pre-scaled by SM_SCALE): rows rh*32..+31, 4 k-chunks
    bf16x8_t qf[4];
#pragma unroll
    for (int kc = 0; kc < 4; kc++)
        qf[kc] = *(const bf16x8_t*)(Qb + ((rh * 4 + kc) << 9) + l * 8);

    float lacc = 0.f;
    f32x16_t oacc[2];
#pragma unroll
    for (int db = 0; db < 2; db++)
#pragma unroll
        for (int r = 0; r < 16; r++) oacc[db][r] = 0.f;

    stage(0, 0);
    __syncthreads();

    const int ntiles = (qt >> 1) + 1;
    const int rowmin = qt * 64 + rh * 32;       // this wave's lowest q-row

    // softmax-finish + PV for one 32-key sub-tile (key base 'base', V/P chunk
    // group 'sub'). st layout: D[key = (reg&3)+8*(reg>>2)+4*lh][row = l31].
    auto finish = [&](f32x16_t& st, int bb, int sub, int base, bool tri) {
        if (tri) {
            const int off = rowmin - base;      // in [-31, 30]
#pragma unroll
            for (int r = 0; r < 16; r++) {
                const int keyl = (r & 3) + 8 * (r >> 2) + 4 * lh;
                st[r] = (keyl > l31 + off) ? 0.f : __expf(st[r]);
            }
        } else {
#pragma unroll
            for (int r = 0; r < 16; r++) st[r] = __expf(st[r]);
        }
#pragma unroll
        for (int r = 0; r < 16; r++) lacc += st[r];
        // O^T += V^T·P : A = V frags, B = P frags built fully in-register.
#pragma unroll
        for (int c = 0; c < 2; c++) {
            unsigned int v0 = cvt_pk_bf16(st[c * 8 + 0], st[c * 8 + 1]);
            unsigned int v1 = cvt_pk_bf16(st[c * 8 + 2], st[c * 8 + 3]);
            unsigned int v2 = cvt_pk_bf16(st[c * 8 + 4], st[c * 8 + 5]);
            unsigned int v3 = cvt_pk_bf16(st[c * 8 + 6], st[c * 8 + 7]);
            // a' = [a.lo | b.lo], b' = [a.hi | b.hi] across the lane halves
            asm("v_permlane32_swap_b32 %0, %1" : "+v"(v0), "+v"(v2));
            asm("v_permlane32_swap_b32 %0, %1" : "+v"(v1), "+v"(v3));
            union { unsigned int u4[4]; bf16x8_t v; } pku;
            pku.u4[0] = v0; pku.u4[1] = v1; pku.u4[2] = v2; pku.u4[3] = v3;
            __builtin_amdgcn_s_setprio(1);
#pragma unroll
            for (int db = 0; db < 2; db++) {
                bf16x8_t vf = *(const bf16x8_t*)
                    &KVs[bb][1][((kh * 8 + db * 4 + sub * 2 + c) << 9) + l * 8];
                oacc[db] = __builtin_amdgcn_mfma_f32_32x32x16_bf16(vf, pku.v, oacc[db], 0, 0, 0);
            }
            __builtin_amdgcn_s_setprio(0);
        }
    };

    for (int t = 0; t < ntiles; t++) {
        const int bb = t & 1;
        if (t + 1 < ntiles) stage(t + 1, bb ^ 1);

        const bool last = (t == ntiles - 1);
        const int base0 = t * 128 + kh * 64;            // sub0 key base
        const bool d0 = !last || (base0      <= rowmin + 31);
        const bool d1 = !last || (base0 + 32 <= rowmin + 31);

        // two independent QK^T chains (always computed; masked waves' results
        // are simply unused — garbage-free since staged K is valid data)
        f32x16_t st0, st1;
#pragma unroll
        for (int r = 0; r < 16; r++) { st0[r] = 0.f; st1[r] = 0.f; }
        __builtin_amdgcn_s_setprio(1);
#pragma unroll
        for (int kc = 0; kc < 4; kc++) {
            bf16x8_t kf0 = *(const bf16x8_t*)&KVs[bb][0][((kh * 8 +     kc) << 9) + l * 8];
            bf16x8_t kf1 = *(const bf16x8_t*)&KVs[bb][0][((kh * 8 + 4 + kc) << 9) + l * 8];
            st0 = __builtin_amdgcn_mfma_f32_32x32x16_bf16(kf0, qf[kc], st0, 0, 0, 0);
            st1 = __builtin_amdgcn_mfma_f32_32x32x16_bf16(kf1, qf[kc], st1, 0, 0, 0);
        }
        __builtin_amdgcn_s_setprio(0);

        if (d0) finish(st0, bb, 0, base0,      last && (base0 + 31 > rowmin));
        if (d1) finish(st1, bb, 1, base0 + 32, last && (base0 + 63 > rowmin));

        __syncthreads();   // reads of buf bb done; prefetch of bb^1 landed
    }

    // ---- key-half combine (linear: no-max softmax) ----
    __syncthreads();                        // KVs reusable as exchange space
    float* Ex = (float*)KVs;                // [rh*64 + lane][34]: 32 O + lacc
    if (kh == 1) {
        float* e = Ex + (rh * 64 + l) * 34;
#pragma unroll
        for (int db = 0; db < 2; db++)
#pragma unroll
            for (int r = 0; r < 16; r++) e[db * 16 + r] = oacc[db][r];
        e[32] = lacc;
    }
    __syncthreads();
    if (kh == 0) {
        const float* e = Ex + (rh * 64 + l) * 34;
#pragma unroll
        for (int db = 0; db < 2; db++)
#pragma unroll
            for (int r = 0; r < 16; r++) oacc[db][r] += e[db * 16 + r];
        lacc += e[32];
        lacc += __shfl_xor(lacc, 32, 64);   // lanes l31 / l31+32 hold same row
        const float rl = 1.f / lacc;
        const int row = qt * 64 + rh * 32 + l31;
#pragma unroll
        for (int db = 0; db < 2; db++)
#pragma unroll
            for (int a = 0; a < 4; a++) {
                union { unsigned short s4[4]; uint2 u; } pk;
#pragma unroll
                for (int i = 0; i < 4; i++) pk.s4[i] = f2bf_bits(oacc[db][a * 4 + i] * rl);
                *(uint2*)(attn + (size_t)row * E_DIM + h * HD + db * 32 + a * 8 + lh * 4) = pk.u;
            }
    }
}

// --------------------------------------------------------- output projection
// 64x128 tile, double-buffered LDS staging (R1 form).
__global__ __launch_bounds__(256) void k_gemm_out(
    const __bf16* __restrict__ A, const __bf16* __restrict__ Bt,
    const float* __restrict__ bias, float* __restrict__ out) {
    __shared__ __align__(16) unsigned short As[2][64 * 32];
    __shared__ __align__(16) unsigned short Bs[2][128 * 32];

    const int tid = threadIdx.x, w = tid >> 6, l = tid & 63;
    const int lm = l & 15, q4 = l >> 4;
    const int bm = blockIdx.y, bn = blockIdx.x;
    const int wm = w >> 1, wn = w & 1;

    const int sm = (w << 4) + (l >> 2);
    const int skk = (l & 3) << 3;
    const __bf16* Ag = A + (size_t)(bm * 64 + sm) * E_DIM + skk;
    const __bf16* Bg = Bt + (size_t)(bn * 128 + sm) * E_DIM + skk;
    const int woff = w << 9;

    f32x4_t acc[2][4];
#pragma unroll
    for (int i = 0; i < 2; i++)
#pragma unroll
        for (int j = 0; j < 4; j++) { acc[i][j].x = 0.f; acc[i][j].y = 0.f; acc[i][j].z = 0.f; acc[i][j].w = 0.f; }

    GLD16(Ag, &As[0][woff]);
    GLD16(Bg, &Bs[0][woff]);
    GLD16(Bg + (size_t)64 * E_DIM, &Bs[0][woff + 2048]);
    __syncthreads();

    for (int s = 0; s < 32; s++) {
        const int bb = s & 1;
        if (s < 31) {
            const int k0 = (s + 1) * 32;
            GLD16(Ag + k0, &As[bb ^ 1][woff]);
            GLD16(Bg + k0, &Bs[bb ^ 1][woff]);
            GLD16(Bg + (size_t)64 * E_DIM + k0, &Bs[bb ^ 1][woff + 2048]);
        }

        bf16x8_t af[2], bfr[4];
#pragma unroll
        for (int mt = 0; mt < 2; mt++)
            af[mt] = *(const bf16x8_t*)&As[bb][(wm * 32 + mt * 16 + lm) * 32 + q4 * 8];
#pragma unroll
        for (int nt = 0; nt < 4; nt++)
            bfr[nt] = *(const bf16x8_t*)&Bs[bb][(wn * 64 + nt * 16 + lm) * 32 + q4 * 8];
#pragma unroll
        for (int mt = 0; mt < 2; mt++)
#pragma unroll
            for (int nt = 0; nt < 4; nt++)
                acc[mt][nt] = __builtin_amdgcn_mfma_f32_16x16x32_bf16(af[mt], bfr[nt], acc[mt][nt], 0, 0, 0);
        __syncthreads();
    }

#pragma unroll
    for (int nt = 0; nt < 4; nt++) {
        const int n = bn * 128 + wn * 64 + nt * 16 + lm;
        const float bval = bias[n];
#pragma unroll
        for (int mt = 0; mt < 2; mt++) {
            const int r0 = bm * 64 + wm * 32 + mt * 16 + q4 * 4;
#pragma unroll
            for (int i = 0; i < 4; i++)
                out[(size_t)(r0 + i) * E_DIM + n] = acc[mt][nt][i] + bval;
        }
    }
}

extern "C" void kernel_launch(void* const* d_in, const int* in_sizes, int n_in,
                              void* d_out, int out_size, void* d_ws, size_t ws_size,
                              hipStream_t stream) {
    const float* x  = (const float*)d_in[0];
    const float* Wq = (const float*)d_in[1];
    const float* bq = (const float*)d_in[2];
    const float* Wk = (const float*)d_in[3];
    const float* bk = (const float*)d_in[4];
    const float* Wv = (const float*)d_in[5];
    const float* bv = (const float*)d_in[6];
    const float* Wo = (const float*)d_in[7];
    const float* bo = (const float*)d_in[8];
    float* out = (float*)d_out;

    char* ws = (char*)d_ws;
    __bf16* xb   = (__bf16*)(ws);                        // 4 MB  x bf16 [S][E]
    __bf16* wt   = (__bf16*)(ws + ((size_t)4  << 20));   // 4x2MB [Wq^T,Wk^T,Wv^T,Wo^T] bf16
    __bf16* qkv  = (__bf16*)(ws + ((size_t)12 << 20));   // op-native Qf,Kf,Vf (4MB each)
    __bf16* attn = (__bf16*)(ws + ((size_t)24 << 20));   // 4 MB  [S][E] bf16

    k_prep<<<dim3(32, 32, 6), dim3(32, 8), 0, stream>>>(x, Wq, Wk, Wv, Wo, xb, wt);
    k_gemm_qkv<<<dim3(E_DIM / 128, S_LEN / 128, 3), 256, 0, stream>>>(xb, wt, bq, bk, bv, qkv);
    k_attn<<<dim3(512), 256, 0, stream>>>(
        qkv, qkv + (size_t)NH * S_LEN * HD, qkv + (size_t)2 * NH * S_LEN * HD, attn);
    k_gemm_out<<<dim3(E_DIM / 128, S_LEN / 64), 256, 0, stream>>>(
        attn, wt + (size_t)3 * E_DIM * E_DIM, bo, out);
}